// Round 2
// baseline (4385.722 us; speedup 1.0000x reference)
//
#include <hip/hip_runtime.h>
#include <hip/hip_bf16.h>
#include <stdint.h>

// GRU-style LanguageEncoder: T=64, B=256, VOCAB=32000, D=512, H=1024.
// NOTE reference semantics: a = tanh(a_x + (r * h) @ w_h_a + b_a)
//   (Python `r * h @ w_h_a` == `(r*h) @ w_h_a` — reset gate BEFORE matmul.)
// Plan:
//   k_gather    : words_bf16[t*B+b][d] = bf16(embed[x]*(x>0))
//   k_transpose : w_i (512x3072) -> wit (3072x512) bf16 ; w_h -> wht (3072x1024) bf16
//   k_zero      : zero h buffer + barrier counters
//   k_gemm_gx   : gx = words @ w_i + b  (16384x3072, bf16 out), 128x128 tile MFMA
//   k_recur     : persistent 256-block kernel, 64 steps, 2 phases/step:
//                 phase Z: zr = sigmoid(gx_zr + h @ w_h_zr); rh = r*h -> global
//                 barrier; phase A: a = tanh(gx_a + rh @ w_h_a); h update; barrier.
//                 Block (m0=64 rows, j0=16 cols): w_h gathered cols {j,H+j,2H+j}
//                 (48 x 1024 bf16, 99KB) persist in LDS. h-patch/z/osum in regs.
//                 Barriers are per-m-group (64 blocks) monotone counters.

#define TT 64
#define BB 256
#define DD 512
#define HH 1024
#define N3H 3072

using frag  = __attribute__((ext_vector_type(8))) short;   // 8 bf16 (4 VGPRs)
using f32x4 = __attribute__((ext_vector_type(4))) float;   // MFMA accumulator

__device__ __forceinline__ uint16_t f2b(float f) {
    uint32_t u = __builtin_bit_cast(uint32_t, f);
    uint32_t r = u + 0x7FFFu + ((u >> 16) & 1u);   // round-to-nearest-even
    return (uint16_t)(r >> 16);
}
__device__ __forceinline__ float b2f(uint16_t b) {
    uint32_t u = ((uint32_t)b) << 16;
    return __builtin_bit_cast(float, u);
}

// ---------------- prep kernels ----------------

__global__ __launch_bounds__(256) void k_gather(const int* __restrict__ x,
                                                const float* __restrict__ embed,
                                                uint16_t* __restrict__ words) {
    // one thread = 8 elems; 16384 rows * 64 chunks = 1,048,576 threads exactly
    int tid = blockIdx.x * 256 + threadIdx.x;
    int row = tid >> 6;
    int c8  = (tid & 63) << 3;
    int tok = x[row];
    float s = (tok > 0) ? 1.f : 0.f;
    const float4* src = (const float4*)(embed + (int64_t)tok * DD + c8);
    float4 v0 = src[0], v1 = src[1];
    float vals[8] = {v0.x, v0.y, v0.z, v0.w, v1.x, v1.y, v1.z, v1.w};
    union { uint16_t u[8]; uint4 q; } pk;
#pragma unroll
    for (int i = 0; i < 8; ++i) pk.u[i] = f2b(vals[i] * s);
    *(uint4*)(words + ((int64_t)row << 9) + c8) = pk.q;
}

// src (K x N) fp32 -> dst (N x K) bf16, 32x32 LDS tiles
__global__ void k_transpose(const float* __restrict__ src, uint16_t* __restrict__ dst,
                            int K, int N) {
    __shared__ float tile[32][33];
    int n0 = blockIdx.x * 32, k0 = blockIdx.y * 32;
    int tx = threadIdx.x, ty = threadIdx.y;   // (32, 8)
#pragma unroll
    for (int i = 0; i < 32; i += 8)
        tile[ty + i][tx] = src[(int64_t)(k0 + ty + i) * N + n0 + tx];
    __syncthreads();
#pragma unroll
    for (int i = 0; i < 32; i += 8)
        dst[(int64_t)(n0 + ty + i) * K + k0 + tx] = f2b(tile[tx][ty + i]);
}

__global__ void k_zero(uint4* p, int n16) {
    int i = blockIdx.x * blockDim.x + threadIdx.x;
    if (i < n16) p[i] = uint4{0u, 0u, 0u, 0u};
}

// ---------------- gx GEMM: 16384 x 3072 x 512 ----------------
// A = words (M x K row-major bf16), BT = wit (N x K row-major bf16)
// 128x128 tile, BK=64, 256 thr = 4 waves, each wave 64x64 (4x4 frags of 16x16x32)

__global__ __launch_bounds__(256) void k_gemm_gx(const uint16_t* __restrict__ A,
                                                 const uint16_t* __restrict__ BT,
                                                 const float* __restrict__ bias,
                                                 uint16_t* __restrict__ C) {
    __shared__ uint16_t As[128][72];   // +8 pad: 2-way (free) instead of 16-way
    __shared__ uint16_t Bs[128][72];
    int m0 = blockIdx.y * 128;
    int n0 = blockIdx.x * 128;
    int t = threadIdx.x;
    int wave = t >> 6, lane = t & 63, quad = lane >> 4, l16 = lane & 15;
    int wm = (wave & 1) * 64, wn = (wave >> 1) * 64;
    f32x4 acc[4][4] = {};

    int sr = t >> 1;              // staging row 0..127
    int sc = (t & 1) * 32;        // staging col 0 or 32

    for (int k0 = 0; k0 < DD; k0 += 64) {
        const uint4* ga = (const uint4*)(A + (int64_t)(m0 + sr) * DD + k0 + sc);
        uint4 a0 = ga[0], a1 = ga[1], a2 = ga[2], a3 = ga[3];
        const uint4* gb = (const uint4*)(BT + (int64_t)(n0 + sr) * DD + k0 + sc);
        uint4 b0 = gb[0], b1 = gb[1], b2 = gb[2], b3 = gb[3];
        __syncthreads();   // previous iteration's reads complete
        *(uint4*)&As[sr][sc]      = a0;
        *(uint4*)&As[sr][sc + 8]  = a1;
        *(uint4*)&As[sr][sc + 16] = a2;
        *(uint4*)&As[sr][sc + 24] = a3;
        *(uint4*)&Bs[sr][sc]      = b0;
        *(uint4*)&Bs[sr][sc + 8]  = b1;
        *(uint4*)&Bs[sr][sc + 16] = b2;
        *(uint4*)&Bs[sr][sc + 24] = b3;
        __syncthreads();
#pragma unroll
        for (int kk = 0; kk < 64; kk += 32) {
            frag af[4], bf[4];
#pragma unroll
            for (int mi = 0; mi < 4; ++mi)
                af[mi] = *(const frag*)&As[wm + mi * 16 + l16][kk + quad * 8];
#pragma unroll
            for (int ni = 0; ni < 4; ++ni)
                bf[ni] = *(const frag*)&Bs[wn + ni * 16 + l16][kk + quad * 8];
#pragma unroll
            for (int mi = 0; mi < 4; ++mi)
#pragma unroll
                for (int ni = 0; ni < 4; ++ni)
                    acc[mi][ni] = __builtin_amdgcn_mfma_f32_16x16x32_bf16(
                        af[mi], bf[ni], acc[mi][ni], 0, 0, 0);
        }
    }
    // epilogue: +bias, bf16 store. C/D: col=lane&15, row=quad*4+reg
#pragma unroll
    for (int ni = 0; ni < 4; ++ni) {
        int col = n0 + wn + ni * 16 + l16;
        float bv = bias[col];
#pragma unroll
        for (int mi = 0; mi < 4; ++mi)
#pragma unroll
            for (int r = 0; r < 4; ++r) {
                int row = m0 + wm + mi * 16 + quad * 4 + r;
                C[(int64_t)row * N3H + col] = f2b(acc[mi][ni][r] + bv);
            }
    }
}

// ---------------- recurrence ----------------
// grid (64 j-strips, 4 m-groups), 256 thr. LDS: Wh[48][1032] bf16 (dynamic, 99KB).
// Gathered Wh rows: [0..15] = w_h col j (z), [16..31] = col H+j (r), [32..47] = col 2H+j (a).

__global__ __launch_bounds__(256, 1) void k_recur(const uint16_t* __restrict__ gx,
                                                  const uint16_t* __restrict__ wht,
                                                  uint16_t* __restrict__ hbuf,
                                                  uint16_t* __restrict__ rhbuf,
                                                  unsigned int* __restrict__ bar,
                                                  float* __restrict__ out) {
    extern __shared__ uint16_t Wh[];           // 48 rows x 1032 (1024 + 8 pad)
    const int LDW = HH + 8;
    int jb = blockIdx.x;        // 0..63
    int mg = blockIdx.y;        // 0..3
    int j0 = jb * 16;
    int m0 = mg * 64;
    int t = threadIdx.x, wave = t >> 6, lane = t & 63, quad = lane >> 4, l16 = lane & 15;

    // load w_h slice: gathered rows s*16+i  <-  wht row s*HH + j0 + i
    for (int c = t; c < 48 * 128; c += 256) {  // 128 x 16B chunks per row
        int row = c >> 7;
        int off = (c & 127) << 3;
        int s = row >> 4, i = row & 15;
        *(uint4*)(Wh + row * LDW + off) =
            *(const uint4*)(wht + (int64_t)(s * HH + j0 + i) * HH + off);
    }
    __syncthreads();

    float hp[4]   = {0.f, 0.f, 0.f, 0.f};   // fp32 h-patch (this lane's 4 rows x 1 col)
    float zg[4];                             // z gate, carried phase Z -> phase A
    float osum[4] = {0.f, 0.f, 0.f, 0.f};   // output accumulator
    int brow = m0 + wave * 16 + quad * 4;    // C-layout base row
    int jcol = j0 + l16;
    unsigned int* cnt = bar + mg * 64;       // 256B apart per group
    unsigned int bidx = 0;                   // barrier index (monotone counter target)

    // A-operand row base offset for this lane (rows m0 + wave*16 + l16)
    const int64_t aoff = (int64_t)(m0 + wave * 16 + l16) * HH + quad * 8;

    for (int step = 0; step < TT; ++step) {
        // ---- barrier: h(step) fully written by all blocks in m-group ----
        if (step > 0) {
            __syncthreads();
            if (t == 0) {
                __threadfence();
                __hip_atomic_fetch_add(cnt, 1u, __ATOMIC_RELEASE, __HIP_MEMORY_SCOPE_AGENT);
                unsigned tgt = (++bidx) * 64u;
                long guard = 0;
                while (__hip_atomic_load(cnt, __ATOMIC_ACQUIRE, __HIP_MEMORY_SCOPE_AGENT) < tgt) {
                    if (++guard > (1L << 22)) break;   // co-residency failsafe
                }
                __threadfence();
            }
            __syncthreads();
        } else {
            bidx = 0;
        }
        if (t != 0) bidx = 0;   // only t0's bidx matters; keep others trivially consistent

        // ---- phase Z: s_zr = h @ w_h_zr (acc0 = z-col, acc1 = r-col) ----
        {
            const uint16_t* arow = hbuf + aoff;
            f32x4 acc0 = {}, acc1 = {};
#pragma unroll 8
            for (int kk = 0; kk < 32; ++kk) {
                frag a  = *(const frag*)(arow + kk * 32);
                frag b0 = *(const frag*)(Wh + (l16)      * LDW + kk * 32 + quad * 8);
                frag b1 = *(const frag*)(Wh + (16 + l16) * LDW + kk * 32 + quad * 8);
                acc0 = __builtin_amdgcn_mfma_f32_16x16x32_bf16(a, b0, acc0, 0, 0, 0);
                acc1 = __builtin_amdgcn_mfma_f32_16x16x32_bf16(a, b1, acc1, 0, 0, 0);
            }
            const uint16_t* gxrow = gx + (int64_t)step * BB * N3H;
#pragma unroll
            for (int r = 0; r < 4; ++r) {
                int bi = brow + r;
                const uint16_t* g = gxrow + (int64_t)bi * N3H;
                float zp = b2f(g[jcol]) + acc0[r];        // bias folded into gx
                float rp = b2f(g[HH + jcol]) + acc1[r];
                float z  = 1.f / (1.f + __expf(-zp));
                float rg = 1.f / (1.f + __expf(-rp));
                zg[r] = z;
                rhbuf[(int64_t)bi * HH + jcol] = f2b(rg * hp[r]);
            }
        }

        // ---- barrier: rh fully written by all blocks in m-group ----
        __syncthreads();
        if (t == 0) {
            __threadfence();
            __hip_atomic_fetch_add(cnt, 1u, __ATOMIC_RELEASE, __HIP_MEMORY_SCOPE_AGENT);
            unsigned tgt = (++bidx) * 64u;
            long guard = 0;
            while (__hip_atomic_load(cnt, __ATOMIC_ACQUIRE, __HIP_MEMORY_SCOPE_AGENT) < tgt) {
                if (++guard > (1L << 22)) break;
            }
            __threadfence();
        }
        __syncthreads();

        // ---- phase A: s_a = rh @ w_h_a (acc2), gate + h update ----
        {
            const uint16_t* arow = rhbuf + aoff;
            f32x4 acc2 = {};
#pragma unroll 8
            for (int kk = 0; kk < 32; ++kk) {
                frag a  = *(const frag*)(arow + kk * 32);
                frag b2 = *(const frag*)(Wh + (32 + l16) * LDW + kk * 32 + quad * 8);
                acc2 = __builtin_amdgcn_mfma_f32_16x16x32_bf16(a, b2, acc2, 0, 0, 0);
            }
            const uint16_t* gxrow = gx + (int64_t)step * BB * N3H;
#pragma unroll
            for (int r = 0; r < 4; ++r) {
                int bi = brow + r;
                const uint16_t* g = gxrow + (int64_t)bi * N3H;
                float ap = b2f(g[2 * HH + jcol]);
                float a  = tanhf(ap + acc2[r]);
                float hn = (1.f - zg[r]) * hp[r] + zg[r] * a;
                osum[r] += hn;
                hp[r] = hn;
                hbuf[(int64_t)bi * HH + jcol] = f2b(hn);   // in-place: safe, all reads done
            }
        }
    }
#pragma unroll
    for (int r = 0; r < 4; ++r)
        out[(int64_t)(brow + r) * HH + jcol] = osum[r];
}

// ---------------- launch ----------------

extern "C" void kernel_launch(void* const* d_in, const int* in_sizes, int n_in,
                              void* d_out, int out_size, void* d_ws, size_t ws_size,
                              hipStream_t stream) {
    const int*   x     = (const int*)d_in[0];
    const float* embed = (const float*)d_in[1];
    const float* w_i   = (const float*)d_in[2];
    const float* w_h   = (const float*)d_in[3];
    const float* bias  = (const float*)d_in[4];
    float* out = (float*)d_out;

    char* ws = (char*)d_ws;
    // ws layout (bytes), all 256-aligned:
    uint16_t* gx    = (uint16_t*)(ws);                 // 16384*3072*2 = 100663296
    uint16_t* wit   = (uint16_t*)(ws + 100663296);     // 3072*512*2  =   3145728
    uint16_t* wht   = (uint16_t*)(ws + 103809024);     // 3072*1024*2 =   6291456
    uint16_t* words = (uint16_t*)(ws + 110100480);     // 16384*512*2 =  16777216
    uint16_t* hbuf  = (uint16_t*)(ws + 126877696);     // 256*1024*2  =    524288
    uint16_t* rhbuf = (uint16_t*)(ws + 127401984);     // 256*1024*2  =    524288
    unsigned int* cnt = (unsigned int*)(ws + 127926272); // 1024

    k_gather<<<4096, 256, 0, stream>>>(x, embed, words);
    k_transpose<<<dim3(96, 16), dim3(32, 8), 0, stream>>>(w_i, wit, DD, N3H);
    k_transpose<<<dim3(96, 32), dim3(32, 8), 0, stream>>>(w_h, wht, HH, N3H);
    // zero h buffer + counters (rhbuf needs no init: written before read)
    k_zero<<<257, 256, 0, stream>>>((uint4*)(ws + 126877696), (1048576 + 1024) / 16);
    k_gemm_gx<<<dim3(24, 128), 256, 0, stream>>>(words, wit, bias, gx);
    k_recur<<<dim3(64, 4), 256, 48 * (HH + 8) * 2, stream>>>(gx, wht, hbuf, rhbuf, cnt, out);
}

// Round 3
// 2876.797 us; speedup vs baseline: 1.5245x; 1.5245x over previous
//
#include <hip/hip_runtime.h>
#include <hip/hip_bf16.h>
#include <stdint.h>

// GRU-style LanguageEncoder: T=64, B=256, VOCAB=32000, D=512, H=1024.
// Reference semantics: a = tanh(a_x + (r * h) @ w_h_a + b_a)  ((r*h) BEFORE matmul).
// Structure:
//   k_gather    : words_bf16[t*B+b][d] = bf16(embed[x]*(x>0))
//   k_transpose : w_i -> wit (3072x512) bf16 ; w_h -> wht (3072x1024) bf16
//   k_zero      : zero h buffer + barrier flags
//   k_gemm_gx   : gx = words @ w_i + b  (16384x3072, bf16), 128x128 MFMA tile
//   k_recur     : persistent 256-block kernel, 64 steps, 2 phases/step.
//                 Block (m-group of 64 rows, j-strip of 16 cols); w_h gathered cols
//                 {j,H+j,2H+j} (48x1024 bf16, 99KB) persist in LDS.
//                 R3 change: flag-array barrier (per-block slot, release store,
//                 64-lane parallel poll) replaces the serialized RMW-chain counter
//                 (R2: 33us/barrier, MfmaUtil 0.96% -> pure sync latency).

#define TT 64
#define BB 256
#define DD 512
#define HH 1024
#define N3H 3072

using frag  = __attribute__((ext_vector_type(8))) short;   // 8 bf16 (4 VGPRs)
using f32x4 = __attribute__((ext_vector_type(4))) float;   // MFMA accumulator

__device__ __forceinline__ uint16_t f2b(float f) {
    uint32_t u = __builtin_bit_cast(uint32_t, f);
    uint32_t r = u + 0x7FFFu + ((u >> 16) & 1u);   // round-to-nearest-even
    return (uint16_t)(r >> 16);
}
__device__ __forceinline__ float b2f(uint16_t b) {
    uint32_t u = ((uint32_t)b) << 16;
    return __builtin_bit_cast(float, u);
}

// ---------------- prep kernels ----------------

__global__ __launch_bounds__(256) void k_gather(const int* __restrict__ x,
                                                const float* __restrict__ embed,
                                                uint16_t* __restrict__ words) {
    int tid = blockIdx.x * 256 + threadIdx.x;
    int row = tid >> 6;
    int c8  = (tid & 63) << 3;
    int tok = x[row];
    float s = (tok > 0) ? 1.f : 0.f;
    const float4* src = (const float4*)(embed + (int64_t)tok * DD + c8);
    float4 v0 = src[0], v1 = src[1];
    float vals[8] = {v0.x, v0.y, v0.z, v0.w, v1.x, v1.y, v1.z, v1.w};
    union { uint16_t u[8]; uint4 q; } pk;
#pragma unroll
    for (int i = 0; i < 8; ++i) pk.u[i] = f2b(vals[i] * s);
    *(uint4*)(words + ((int64_t)row << 9) + c8) = pk.q;
}

// src (K x N) fp32 -> dst (N x K) bf16, 32x32 LDS tiles
__global__ void k_transpose(const float* __restrict__ src, uint16_t* __restrict__ dst,
                            int K, int N) {
    __shared__ float tile[32][33];
    int n0 = blockIdx.x * 32, k0 = blockIdx.y * 32;
    int tx = threadIdx.x, ty = threadIdx.y;   // (32, 8)
#pragma unroll
    for (int i = 0; i < 32; i += 8)
        tile[ty + i][tx] = src[(int64_t)(k0 + ty + i) * N + n0 + tx];
    __syncthreads();
#pragma unroll
    for (int i = 0; i < 32; i += 8)
        dst[(int64_t)(n0 + ty + i) * K + k0 + tx] = f2b(tile[tx][ty + i]);
}

__global__ void k_zero(uint4* p, int n16) {
    int i = blockIdx.x * blockDim.x + threadIdx.x;
    if (i < n16) p[i] = uint4{0u, 0u, 0u, 0u};
}

// ---------------- gx GEMM: 16384 x 3072 x 512 ----------------

__global__ __launch_bounds__(256) void k_gemm_gx(const uint16_t* __restrict__ A,
                                                 const uint16_t* __restrict__ BT,
                                                 const float* __restrict__ bias,
                                                 uint16_t* __restrict__ C) {
    __shared__ uint16_t As[128][72];
    __shared__ uint16_t Bs[128][72];
    int m0 = blockIdx.y * 128;
    int n0 = blockIdx.x * 128;
    int t = threadIdx.x;
    int wave = t >> 6, lane = t & 63, quad = lane >> 4, l16 = lane & 15;
    int wm = (wave & 1) * 64, wn = (wave >> 1) * 64;
    f32x4 acc[4][4] = {};

    int sr = t >> 1;
    int sc = (t & 1) * 32;

    for (int k0 = 0; k0 < DD; k0 += 64) {
        const uint4* ga = (const uint4*)(A + (int64_t)(m0 + sr) * DD + k0 + sc);
        uint4 a0 = ga[0], a1 = ga[1], a2 = ga[2], a3 = ga[3];
        const uint4* gb = (const uint4*)(BT + (int64_t)(n0 + sr) * DD + k0 + sc);
        uint4 b0 = gb[0], b1 = gb[1], b2 = gb[2], b3 = gb[3];
        __syncthreads();
        *(uint4*)&As[sr][sc]      = a0;
        *(uint4*)&As[sr][sc + 8]  = a1;
        *(uint4*)&As[sr][sc + 16] = a2;
        *(uint4*)&As[sr][sc + 24] = a3;
        *(uint4*)&Bs[sr][sc]      = b0;
        *(uint4*)&Bs[sr][sc + 8]  = b1;
        *(uint4*)&Bs[sr][sc + 16] = b2;
        *(uint4*)&Bs[sr][sc + 24] = b3;
        __syncthreads();
#pragma unroll
        for (int kk = 0; kk < 64; kk += 32) {
            frag af[4], bf[4];
#pragma unroll
            for (int mi = 0; mi < 4; ++mi)
                af[mi] = *(const frag*)&As[wm + mi * 16 + l16][kk + quad * 8];
#pragma unroll
            for (int ni = 0; ni < 4; ++ni)
                bf[ni] = *(const frag*)&Bs[wn + ni * 16 + l16][kk + quad * 8];
#pragma unroll
            for (int mi = 0; mi < 4; ++mi)
#pragma unroll
                for (int ni = 0; ni < 4; ++ni)
                    acc[mi][ni] = __builtin_amdgcn_mfma_f32_16x16x32_bf16(
                        af[mi], bf[ni], acc[mi][ni], 0, 0, 0);
        }
    }
#pragma unroll
    for (int ni = 0; ni < 4; ++ni) {
        int col = n0 + wn + ni * 16 + l16;
        float bv = bias[col];
#pragma unroll
        for (int mi = 0; mi < 4; ++mi)
#pragma unroll
            for (int r = 0; r < 4; ++r) {
                int row = m0 + wm + mi * 16 + quad * 4 + r;
                C[(int64_t)row * N3H + col] = f2b(acc[mi][ni][r] + bv);
            }
    }
}

// ---------------- recurrence ----------------
// grid (mg=4, jb=64) so linear id = mg + 4*jb -> each m-group's 64 blocks sit on
// XCDs {mg, mg+4} only (i%8 round-robin). LDS: Wh[48][1032] bf16 (99KB).

__global__ __launch_bounds__(256, 1) void k_recur(const uint16_t* __restrict__ gx,
                                                  const uint16_t* __restrict__ wht,
                                                  uint16_t* __restrict__ hbuf,
                                                  uint16_t* __restrict__ rhbuf,
                                                  unsigned int* __restrict__ bar,
                                                  float* __restrict__ out) {
    extern __shared__ uint16_t Wh[];           // 48 rows x 1032 (1024 + 8 pad)
    const int LDW = HH + 8;
    int mg = blockIdx.x;        // 0..3  (fast dim -> XCD pairing)
    int jb = blockIdx.y;        // 0..63
    int j0 = jb * 16;
    int m0 = mg * 64;
    int t = threadIdx.x, wave = t >> 6, lane = t & 63, quad = lane >> 4, l16 = lane & 15;

    // load w_h slice: gathered rows s*16+i  <-  wht row s*HH + j0 + i
    for (int c = t; c < 48 * 128; c += 256) {
        int row = c >> 7;
        int off = (c & 127) << 3;
        int s = row >> 4, i = row & 15;
        *(uint4*)(Wh + row * LDW + off) =
            *(const uint4*)(wht + (int64_t)(s * HH + j0 + i) * HH + off);
    }
    __syncthreads();

    float hp[4]   = {0.f, 0.f, 0.f, 0.f};
    float zg[4];
    float osum[4] = {0.f, 0.f, 0.f, 0.f};
    int brow = m0 + wave * 16 + quad * 4;
    int jcol = j0 + l16;
    unsigned int* flags = bar + mg * 64;     // one 4B slot per block in group
    unsigned int phase = 0;

    const int64_t aoff = (int64_t)(m0 + wave * 16 + l16) * HH + quad * 8;

    // flag-array barrier: release my slot, wave0 polls all 64 slots in parallel
    auto group_barrier = [&](unsigned int ph) {
        __syncthreads();                       // each wave drains its stores (vmcnt0)
        if (t == 0) {
            __threadfence();                   // flush h/rh to device scope
            __hip_atomic_store(&flags[jb], ph, __ATOMIC_RELEASE, __HIP_MEMORY_SCOPE_AGENT);
        }
        if (wave == 0) {
            long guard = 0;
            for (;;) {
                unsigned int v = __hip_atomic_load(&flags[lane], __ATOMIC_RELAXED,
                                                   __HIP_MEMORY_SCOPE_AGENT);
                if (__all((int)(v >= ph))) break;
                __builtin_amdgcn_s_sleep(1);
                if (++guard > (1L << 18)) break;   // co-residency failsafe
            }
        }
        if (t == 0) __threadfence();           // acquire: invalidate for fresh reads
        __syncthreads();
    };

    for (int step = 0; step < TT; ++step) {
        // prefetch this step's gx scalars (immutable) - latency hides under barrier
        uint16_t gzv[4], grv[4], gav[4];
        {
            const uint16_t* gxrow = gx + (int64_t)step * BB * N3H;
#pragma unroll
            for (int r = 0; r < 4; ++r) {
                const uint16_t* g = gxrow + (int64_t)(brow + r) * N3H + jcol;
                gzv[r] = g[0]; grv[r] = g[HH]; gav[r] = g[2 * HH];
            }
        }

        // ---- barrier: h(step) fully written by all blocks in m-group ----
        if (step > 0) group_barrier(++phase);

        // ---- phase Z: h @ w_h_zr (acc0 = z-col, acc1 = r-col) ----
        {
            const uint16_t* arow = hbuf + aoff;
            f32x4 acc0 = {}, acc1 = {};
#pragma unroll 8
            for (int kk = 0; kk < 32; ++kk) {
                frag a  = *(const frag*)(arow + kk * 32);
                frag b0 = *(const frag*)(Wh + (l16)      * LDW + kk * 32 + quad * 8);
                frag b1 = *(const frag*)(Wh + (16 + l16) * LDW + kk * 32 + quad * 8);
                acc0 = __builtin_amdgcn_mfma_f32_16x16x32_bf16(a, b0, acc0, 0, 0, 0);
                acc1 = __builtin_amdgcn_mfma_f32_16x16x32_bf16(a, b1, acc1, 0, 0, 0);
            }
#pragma unroll
            for (int r = 0; r < 4; ++r) {
                int bi = brow + r;
                float zp = b2f(gzv[r]) + acc0[r];        // bias folded into gx
                float rp = b2f(grv[r]) + acc1[r];
                float z  = 1.f / (1.f + __expf(-zp));
                float rg = 1.f / (1.f + __expf(-rp));
                zg[r] = z;
                rhbuf[(int64_t)bi * HH + jcol] = f2b(rg * hp[r]);
            }
        }

        // ---- barrier: rh fully written by all blocks in m-group ----
        group_barrier(++phase);

        // ---- phase A: rh @ w_h_a (acc2), gate + h update ----
        {
            const uint16_t* arow = rhbuf + aoff;
            f32x4 acc2 = {};
#pragma unroll 8
            for (int kk = 0; kk < 32; ++kk) {
                frag a  = *(const frag*)(arow + kk * 32);
                frag b2 = *(const frag*)(Wh + (32 + l16) * LDW + kk * 32 + quad * 8);
                acc2 = __builtin_amdgcn_mfma_f32_16x16x32_bf16(a, b2, acc2, 0, 0, 0);
            }
#pragma unroll
            for (int r = 0; r < 4; ++r) {
                int bi = brow + r;
                float a  = tanhf(b2f(gav[r]) + acc2[r]);
                float hn = (1.f - zg[r]) * hp[r] + zg[r] * a;
                osum[r] += hn;
                hp[r] = hn;
                hbuf[(int64_t)bi * HH + jcol] = f2b(hn);   // in-place: all reads done
            }
        }
    }
#pragma unroll
    for (int r = 0; r < 4; ++r)
        out[(int64_t)(brow + r) * HH + jcol] = osum[r];
}

// ---------------- launch ----------------

extern "C" void kernel_launch(void* const* d_in, const int* in_sizes, int n_in,
                              void* d_out, int out_size, void* d_ws, size_t ws_size,
                              hipStream_t stream) {
    const int*   x     = (const int*)d_in[0];
    const float* embed = (const float*)d_in[1];
    const float* w_i   = (const float*)d_in[2];
    const float* w_h   = (const float*)d_in[3];
    const float* bias  = (const float*)d_in[4];
    float* out = (float*)d_out;

    char* ws = (char*)d_ws;
    uint16_t* gx    = (uint16_t*)(ws);                 // 16384*3072*2 = 100663296
    uint16_t* wit   = (uint16_t*)(ws + 100663296);     // 3072*512*2  =   3145728
    uint16_t* wht   = (uint16_t*)(ws + 103809024);     // 3072*1024*2 =   6291456
    uint16_t* words = (uint16_t*)(ws + 110100480);     // 16384*512*2 =  16777216
    uint16_t* hbuf  = (uint16_t*)(ws + 126877696);     // 256*1024*2  =    524288
    uint16_t* rhbuf = (uint16_t*)(ws + 127401984);     // 256*1024*2  =    524288
    unsigned int* flags = (unsigned int*)(ws + 127926272); // 4*64*4 = 1024

    k_gather<<<4096, 256, 0, stream>>>(x, embed, words);
    k_transpose<<<dim3(96, 16), dim3(32, 8), 0, stream>>>(w_i, wit, DD, N3H);
    k_transpose<<<dim3(96, 32), dim3(32, 8), 0, stream>>>(w_h, wht, HH, N3H);
    // zero hbuf + rhbuf + flags (contiguous 1048576 + 1024 bytes)
    k_zero<<<257, 256, 0, stream>>>((uint4*)(ws + 126877696), (1048576 + 1024) / 16);
    k_gemm_gx<<<dim3(24, 128), 256, 0, stream>>>(words, wit, bias, gx);
    k_recur<<<dim3(4, 64), 256, 48 * (HH + 8) * 2, stream>>>(gx, wht, hbuf, rhbuf, flags, out);
}

// Round 6
// 2232.052 us; speedup vs baseline: 1.9649x; 1.2889x over previous
//
#include <hip/hip_runtime.h>
#include <hip/hip_bf16.h>
#include <stdint.h>

// GRU-style LanguageEncoder: T=64, B=256, VOCAB=32000, D=512, H=1024.
// Reference semantics: a = tanh(a_x + (r * h) @ w_h_a + b_a)  ((r*h) BEFORE matmul).
// Structure:
//   k_gather    : words_bf16[t*B+b][d] = bf16(embed[x]*(x>0))
//   k_transpose : w_i -> wit (3072x512) bf16 ; w_h -> wht (3072x1024) bf16
//   k_zero      : zero h buffer + barrier flags
//   k_gemm_gx   : gx = words @ w_i + b  (16384x3072, bf16), 128x128 MFMA tile
//   k_recur     : persistent 256-block kernel, 64 steps, 2 phases/step.
//                 R2: RMW-counter barrier + threadfence -> 33us/phase.
//                 R3: flag-array barrier + threadfence -> 21.5us/phase (fence =
//                     buffer_wbl2 + buffer_inv L2 walks dominate).
//                 R6: NO fences. All cross-block WRITES are atomic RMWs
//                 (exchange/fetch_add -> architecturally performed at L3
//                 coherence point; R2 proved cross-XCD RMW visibility). All
//                 cross-block READS are relaxed agent-scope sc1 loads (bypass
//                 stale L2; R3's poll proved they observe remote L3 state).
//                 __syncthreads' vmcnt(0) drain orders data RMWs before the
//                 flag RMW. Guard capped at 2^13 polls so a broken barrier
//                 fails absmax in <0.5s instead of wedging the container.

#define TT 64
#define BB 256
#define DD 512
#define HH 1024
#define N3H 3072

using frag  = __attribute__((ext_vector_type(8))) short;   // 8 bf16 (4 VGPRs)
using f32x4 = __attribute__((ext_vector_type(4))) float;   // MFMA accumulator

__device__ __forceinline__ uint16_t f2b(float f) {
    uint32_t u = __builtin_bit_cast(uint32_t, f);
    uint32_t r = u + 0x7FFFu + ((u >> 16) & 1u);   // round-to-nearest-even
    return (uint16_t)(r >> 16);
}
__device__ __forceinline__ float b2f(uint16_t b) {
    uint32_t u = ((uint32_t)b) << 16;
    return __builtin_bit_cast(float, u);
}

// coherent (L3-read, L2-bypassing) 16B fragment load from 4B relaxed atomics
__device__ __forceinline__ frag load_frag_coh(uint32_t* p) {
    union { uint32_t u[4]; frag f; } w;
#pragma unroll
    for (int i = 0; i < 4; ++i)
        w.u[i] = __hip_atomic_load(p + i, __ATOMIC_RELAXED, __HIP_MEMORY_SCOPE_AGENT);
    return w.f;
}
// coherent store: RMW-exchange -> guaranteed performed at the L3 coherence point
__device__ __forceinline__ void store_coh(uint32_t* p, uint32_t v) {
    (void)__hip_atomic_exchange(p, v, __ATOMIC_RELAXED, __HIP_MEMORY_SCOPE_AGENT);
}

// ---------------- prep kernels ----------------

__global__ __launch_bounds__(256) void k_gather(const int* __restrict__ x,
                                                const float* __restrict__ embed,
                                                uint16_t* __restrict__ words) {
    int tid = blockIdx.x * 256 + threadIdx.x;
    int row = tid >> 6;
    int c8  = (tid & 63) << 3;
    int tok = x[row];
    float s = (tok > 0) ? 1.f : 0.f;
    const float4* src = (const float4*)(embed + (int64_t)tok * DD + c8);
    float4 v0 = src[0], v1 = src[1];
    float vals[8] = {v0.x, v0.y, v0.z, v0.w, v1.x, v1.y, v1.z, v1.w};
    union { uint16_t u[8]; uint4 q; } pk;
#pragma unroll
    for (int i = 0; i < 8; ++i) pk.u[i] = f2b(vals[i] * s);
    *(uint4*)(words + ((int64_t)row << 9) + c8) = pk.q;
}

// src (K x N) fp32 -> dst (N x K) bf16, 32x32 LDS tiles
__global__ void k_transpose(const float* __restrict__ src, uint16_t* __restrict__ dst,
                            int K, int N) {
    __shared__ float tile[32][33];
    int n0 = blockIdx.x * 32, k0 = blockIdx.y * 32;
    int tx = threadIdx.x, ty = threadIdx.y;   // (32, 8)
#pragma unroll
    for (int i = 0; i < 32; i += 8)
        tile[ty + i][tx] = src[(int64_t)(k0 + ty + i) * N + n0 + tx];
    __syncthreads();
#pragma unroll
    for (int i = 0; i < 32; i += 8)
        dst[(int64_t)(n0 + ty + i) * K + k0 + tx] = f2b(tile[tx][ty + i]);
}

__global__ void k_zero(uint4* p, int n16) {
    int i = blockIdx.x * blockDim.x + threadIdx.x;
    if (i < n16) p[i] = uint4{0u, 0u, 0u, 0u};
}

// ---------------- gx GEMM: 16384 x 3072 x 512 ----------------

__global__ __launch_bounds__(256) void k_gemm_gx(const uint16_t* __restrict__ A,
                                                 const uint16_t* __restrict__ BT,
                                                 const float* __restrict__ bias,
                                                 uint16_t* __restrict__ C) {
    __shared__ uint16_t As[128][72];
    __shared__ uint16_t Bs[128][72];
    int m0 = blockIdx.y * 128;
    int n0 = blockIdx.x * 128;
    int t = threadIdx.x;
    int wave = t >> 6, lane = t & 63, quad = lane >> 4, l16 = lane & 15;
    int wm = (wave & 1) * 64, wn = (wave >> 1) * 64;
    f32x4 acc[4][4] = {};

    int sr = t >> 1;
    int sc = (t & 1) * 32;

    for (int k0 = 0; k0 < DD; k0 += 64) {
        const uint4* ga = (const uint4*)(A + (int64_t)(m0 + sr) * DD + k0 + sc);
        uint4 a0 = ga[0], a1 = ga[1], a2 = ga[2], a3 = ga[3];
        const uint4* gb = (const uint4*)(BT + (int64_t)(n0 + sr) * DD + k0 + sc);
        uint4 b0 = gb[0], b1 = gb[1], b2 = gb[2], b3 = gb[3];
        __syncthreads();
        *(uint4*)&As[sr][sc]      = a0;
        *(uint4*)&As[sr][sc + 8]  = a1;
        *(uint4*)&As[sr][sc + 16] = a2;
        *(uint4*)&As[sr][sc + 24] = a3;
        *(uint4*)&Bs[sr][sc]      = b0;
        *(uint4*)&Bs[sr][sc + 8]  = b1;
        *(uint4*)&Bs[sr][sc + 16] = b2;
        *(uint4*)&Bs[sr][sc + 24] = b3;
        __syncthreads();
#pragma unroll
        for (int kk = 0; kk < 64; kk += 32) {
            frag af[4], bf[4];
#pragma unroll
            for (int mi = 0; mi < 4; ++mi)
                af[mi] = *(const frag*)&As[wm + mi * 16 + l16][kk + quad * 8];
#pragma unroll
            for (int ni = 0; ni < 4; ++ni)
                bf[ni] = *(const frag*)&Bs[wn + ni * 16 + l16][kk + quad * 8];
#pragma unroll
            for (int mi = 0; mi < 4; ++mi)
#pragma unroll
                for (int ni = 0; ni < 4; ++ni)
                    acc[mi][ni] = __builtin_amdgcn_mfma_f32_16x16x32_bf16(
                        af[mi], bf[ni], acc[mi][ni], 0, 0, 0);
        }
    }
#pragma unroll
    for (int ni = 0; ni < 4; ++ni) {
        int col = n0 + wn + ni * 16 + l16;
        float bv = bias[col];
#pragma unroll
        for (int mi = 0; mi < 4; ++mi)
#pragma unroll
            for (int r = 0; r < 4; ++r) {
                int row = m0 + wm + mi * 16 + quad * 4 + r;
                C[(int64_t)row * N3H + col] = f2b(acc[mi][ni][r] + bv);
            }
    }
}

// ---------------- recurrence ----------------
// grid (mg=4, jb=64): linear id = mg + 4*jb -> each m-group's 64 blocks sit on
// XCDs {mg, mg+4} (i%8 round-robin). LDS: Wh[48][1032] bf16 (99KB).
// Flags: one 4B slot per block, 64B apart; group mg owns bar[mg*1024 + jb*16].

__global__ __launch_bounds__(256, 1) void k_recur(const uint16_t* __restrict__ gx,
                                                  const uint16_t* __restrict__ wht,
                                                  uint16_t* __restrict__ hbuf,
                                                  uint16_t* __restrict__ rhbuf,
                                                  unsigned int* __restrict__ bar,
                                                  float* __restrict__ out) {
    extern __shared__ uint16_t Wh[];           // 48 rows x 1032 (1024 + 8 pad)
    const int LDW = HH + 8;
    int mg = blockIdx.x;        // 0..3  (fast dim -> XCD pairing)
    int jb = blockIdx.y;        // 0..63
    int j0 = jb * 16;
    int m0 = mg * 64;
    int t = threadIdx.x, wave = t >> 6, lane = t & 63, quad = lane >> 4, l16 = lane & 15;

    // load w_h slice: gathered rows s*16+i  <-  wht row s*HH + j0 + i
    for (int c = t; c < 48 * 128; c += 256) {
        int row = c >> 7;
        int off = (c & 127) << 3;
        int s = row >> 4, i = row & 15;
        *(uint4*)(Wh + row * LDW + off) =
            *(const uint4*)(wht + (int64_t)(s * HH + j0 + i) * HH + off);
    }
    __syncthreads();

    float hp[4]   = {0.f, 0.f, 0.f, 0.f};
    float zg[4];
    float osum[4] = {0.f, 0.f, 0.f, 0.f};
    int brow = m0 + wave * 16 + quad * 4;
    int jcol = j0 + l16;
    unsigned int* flags = bar + mg * 1024;   // 64 slots x 64B stride
    unsigned int phase = 0;

    // A-operand base (this lane's MFMA A rows), as uint32 index (even offsets)
    const int64_t aoff = (int64_t)(m0 + wave * 16 + l16) * HH + quad * 8;
    uint32_t* h32  = (uint32_t*)hbuf  + (aoff >> 1);
    uint32_t* rh32 = (uint32_t*)rhbuf + (aoff >> 1);
    // store base: even-l16 lanes store packed pairs (col l16, l16+1)
    const int jc2 = j0 + (l16 & ~1);

    // arrive: drain my data RMWs (syncthreads -> vmcnt(0)), then RMW my flag slot.
    auto bar_arrive = [&]() {
        __syncthreads();
        if (t == 0)
            (void)__hip_atomic_fetch_add(&flags[jb * 16], 1u, __ATOMIC_RELAXED,
                                         __HIP_MEMORY_SCOPE_AGENT);
    };
    // wait: wave0 polls all 64 slots in parallel with relaxed sc1 loads.
    auto bar_wait = [&](unsigned int ph) {
        if (wave == 0) {
            long guard = 0;
            for (;;) {
                unsigned int v = __hip_atomic_load(&flags[lane * 16], __ATOMIC_RELAXED,
                                                   __HIP_MEMORY_SCOPE_AGENT);
                if (__all((int)(v >= ph))) break;
                __builtin_amdgcn_s_sleep(2);
                if (++guard > (1L << 13)) break;   // fail fast (absmax), never wedge
            }
        }
        __syncthreads();
    };

    for (int step = 0; step < TT; ++step) {
        // ---- barrier: h(step) fully written by all blocks in m-group ----
        if (step > 0) bar_arrive();

        // prefetch this step's gx scalars (immutable, normal cached loads);
        // issued between arrive and wait so latency hides under the poll
        uint16_t gzv[4], grv[4], gav[4];
        {
            const uint16_t* gxrow = gx + (int64_t)step * BB * N3H;
#pragma unroll
            for (int r = 0; r < 4; ++r) {
                const uint16_t* g = gxrow + (int64_t)(brow + r) * N3H + jcol;
                gzv[r] = g[0]; grv[r] = g[HH]; gav[r] = g[2 * HH];
            }
        }

        if (step > 0) bar_wait(++phase);

        // ---- phase Z: h @ w_h_zr (acc0 = z-col, acc1 = r-col) ----
        {
            f32x4 acc0 = {}, acc1 = {};
#pragma unroll 8
            for (int kk = 0; kk < 32; ++kk) {
                frag a  = load_frag_coh(h32 + kk * 16);
                frag b0 = *(const frag*)(Wh + (l16)      * LDW + kk * 32 + quad * 8);
                frag b1 = *(const frag*)(Wh + (16 + l16) * LDW + kk * 32 + quad * 8);
                acc0 = __builtin_amdgcn_mfma_f32_16x16x32_bf16(a, b0, acc0, 0, 0, 0);
                acc1 = __builtin_amdgcn_mfma_f32_16x16x32_bf16(a, b1, acc1, 0, 0, 0);
            }
#pragma unroll
            for (int r = 0; r < 4; ++r) {
                float zp = b2f(gzv[r]) + acc0[r];        // bias folded into gx
                float rp = b2f(grv[r]) + acc1[r];
                float z  = 1.f / (1.f + __expf(-zp));
                float rg = 1.f / (1.f + __expf(-rp));
                zg[r] = z;
                uint32_t mine = f2b(rg * hp[r]);
                uint32_t oth  = __shfl_xor(mine, 1);
                if (!(l16 & 1))
                    store_coh((uint32_t*)rhbuf + (int64_t)(brow + r) * (HH / 2) + (jc2 >> 1),
                              mine | (oth << 16));
            }
        }

        // ---- barrier: rh fully written by all blocks in m-group ----
        bar_arrive();
        bar_wait(++phase);

        // ---- phase A: rh @ w_h_a (acc2), gate + h update ----
        {
            f32x4 acc2 = {};
#pragma unroll 8
            for (int kk = 0; kk < 32; ++kk) {
                frag a  = load_frag_coh(rh32 + kk * 16);
                frag b2 = *(const frag*)(Wh + (32 + l16) * LDW + kk * 32 + quad * 8);
                acc2 = __builtin_amdgcn_mfma_f32_16x16x32_bf16(a, b2, acc2, 0, 0, 0);
            }
#pragma unroll
            for (int r = 0; r < 4; ++r) {
                float a  = tanhf(b2f(gav[r]) + acc2[r]);
                float hn = (1.f - zg[r]) * hp[r] + zg[r] * a;
                osum[r] += hn;
                hp[r] = hn;
                uint32_t mine = f2b(hn);
                uint32_t oth  = __shfl_xor(mine, 1);
                if (!(l16 & 1))
                    store_coh((uint32_t*)hbuf + (int64_t)(brow + r) * (HH / 2) + (jc2 >> 1),
                              mine | (oth << 16));
            }
        }
    }
#pragma unroll
    for (int r = 0; r < 4; ++r)
        out[(int64_t)(brow + r) * HH + jcol] = osum[r];
}

// ---------------- launch ----------------

extern "C" void kernel_launch(void* const* d_in, const int* in_sizes, int n_in,
                              void* d_out, int out_size, void* d_ws, size_t ws_size,
                              hipStream_t stream) {
    const int*   x     = (const int*)d_in[0];
    const float* embed = (const float*)d_in[1];
    const float* w_i   = (const float*)d_in[2];
    const float* w_h   = (const float*)d_in[3];
    const float* bias  = (const float*)d_in[4];
    float* out = (float*)d_out;

    char* ws = (char*)d_ws;
    uint16_t* gx    = (uint16_t*)(ws);                 // 16384*3072*2 = 100663296
    uint16_t* wit   = (uint16_t*)(ws + 100663296);     // 3072*512*2  =   3145728
    uint16_t* wht   = (uint16_t*)(ws + 103809024);     // 3072*1024*2 =   6291456
    uint16_t* words = (uint16_t*)(ws + 110100480);     // 16384*512*2 =  16777216
    uint16_t* hbuf  = (uint16_t*)(ws + 126877696);     // 256*1024*2  =    524288
    uint16_t* rhbuf = (uint16_t*)(ws + 127401984);     // 256*1024*2  =    524288
    unsigned int* flags = (unsigned int*)(ws + 127926272); // 4*1024*4 = 16384

    k_gather<<<4096, 256, 0, stream>>>(x, embed, words);
    k_transpose<<<dim3(96, 16), dim3(32, 8), 0, stream>>>(w_i, wit, DD, N3H);
    k_transpose<<<dim3(96, 32), dim3(32, 8), 0, stream>>>(w_h, wht, HH, N3H);
    // zero hbuf + rhbuf + flags (contiguous 1048576 + 16384 bytes)
    k_zero<<<261, 256, 0, stream>>>((uint4*)(ws + 126877696), (1048576 + 16384) / 16);
    k_gemm_gx<<<dim3(24, 128), 256, 0, stream>>>(words, wit, bias, gx);
    k_recur<<<dim3(4, 64), 256, 48 * (HH + 8) * 2, stream>>>(gx, wht, hbuf, rhbuf, flags, out);
}